// Round 1
// baseline (793.746 us; speedup 1.0000x reference)
//
#include <hip/hip_runtime.h>

typedef unsigned short u16;
typedef float f32x4 __attribute__((ext_vector_type(4)));
typedef __bf16 bf16x8 __attribute__((ext_vector_type(8)));
typedef u16 u16x8 __attribute__((ext_vector_type(8)));

static __device__ __forceinline__ u16 f2bf(float f) {
  union { float f; unsigned u; } v; v.f = f;
  unsigned r = v.u + 0x7fffu + ((v.u >> 16) & 1u);  // RNE
  return (u16)(r >> 16);
}

static __device__ __forceinline__ f32x4 mfma16(u16x8 a, u16x8 b, f32x4 c) {
  return __builtin_amdgcn_mfma_f32_16x16x32_bf16(
      __builtin_bit_cast(bf16x8, a), __builtin_bit_cast(bf16x8, b), c, 0, 0, 0);
}

static __device__ __forceinline__ void load_lds16(const void* g, void* l) {
  __builtin_amdgcn_global_load_lds(
      (const __attribute__((address_space(1))) void*)g,
      (__attribute__((address_space(3))) void*)l, 16, 0, 0);
}

// ---------------- elementwise f32 -> bf16 ----------------
__global__ void cvt_f32_bf16(const float* __restrict__ in, u16* __restrict__ out, int n4) {
  int i = blockIdx.x * blockDim.x + threadIdx.x;
  if (i >= n4) return;
  float4 v = ((const float4*)in)[i];
  ushort4 o;
  o.x = f2bf(v.x); o.y = f2bf(v.y); o.z = f2bf(v.z); o.w = f2bf(v.w);
  ((ushort4*)out)[i] = o;
}

// ---------------- transpose + convert: W[K][N] f32 -> Wt[N][K] bf16 ----------------
__global__ __launch_bounds__(256)
void transpose_cvt(const float* __restrict__ W, u16* __restrict__ Wt, int K, int N) {
  __shared__ float tile[32][33];
  int tx = threadIdx.x & 31, ty = threadIdx.x >> 5;
  int k0 = blockIdx.x * 32, n0 = blockIdx.y * 32;
  #pragma unroll
  for (int i = ty; i < 32; i += 8)
    tile[i][tx] = W[(size_t)(k0 + i) * N + (n0 + tx)];
  __syncthreads();
  #pragma unroll
  for (int i = ty; i < 32; i += 8)
    Wt[(size_t)(n0 + i) * K + (k0 + tx)] = f2bf(tile[tx][i]);
}

// ---------------- RoPE cos/sin table: [L][64] float2 ----------------
__global__ void rope_table_k(float2* __restrict__ tab, const int* __restrict__ start, int L) {
  int i = blockIdx.x * blockDim.x + threadIdx.x;
  if (i >= L * 64) return;
  int p = i >> 6, j = i & 63;
  float inv = powf(10000.0f, -(float)j / 64.0f);
  float ang = (float)(p + start[0]) * inv;
  tab[i] = make_float2(cosf(ang), sinf(ang));
}

// ---------------- RoPE apply: q f32 [L][H][128] -> bf16 (rotate-half) ----------------
__global__ void rope_apply_k(const float* __restrict__ qin, u16* __restrict__ qout,
                             const float2* __restrict__ tab, int L, int H) {
  int i = blockIdx.x * blockDim.x + threadIdx.x;
  if (i >= L * H * 64) return;
  int j = i & 63;
  int h = (i >> 6) % H;
  int p = i / (64 * H);
  size_t base = ((size_t)p * H + h) * 128;
  float2 cs = tab[p * 64 + j];
  float a = qin[base + j], b = qin[base + j + 64];
  qout[base + j]      = f2bf(a * cs.x - b * cs.y);
  qout[base + j + 64] = f2bf(a * cs.y + b * cs.x);
}

// ---------------- GEMM: C[M][N] = A[M][K](bf16) @ Bt[N][K](bf16) ----------------
// m97 structure: 128x128 tile, BK=32, 4 waves (2x2 of 64x64), global_load_lds w=16.
template<bool OUT_BF16>
__global__ __launch_bounds__(256)
void gemm_bt(const u16* __restrict__ A, const u16* __restrict__ Bt,
             float* __restrict__ Cf, u16* __restrict__ Cb, int M, int N, int K) {
  __shared__ alignas(16) u16 As[128 * 32];
  __shared__ alignas(16) u16 Bs[128 * 32];
  const int tid = threadIdx.x;
  const int lane = tid & 63, wave = tid >> 6;
  const int ql = lane & 15, kg = lane >> 4;
  const int m0 = blockIdx.x * 128, n0 = blockIdx.y * 128;
  const int wm = (wave >> 1) * 64, wn = (wave & 1) * 64;

  f32x4 acc[4][4] = {};

  // staging chunks: c = t*256 + tid -> lds byte off c*16 = base(t,wave) + lane*16
  const int c0 = tid, c1 = 256 + tid;
  const int r0 = c0 >> 2, e0 = (c0 & 3) * 8;
  const int r1 = c1 >> 2, e1 = (c1 & 3) * 8;
  const u16* a0 = A + (size_t)(m0 + r0) * K + e0;
  const u16* a1 = A + (size_t)(m0 + r1) * K + e1;
  const u16* b0 = Bt + (size_t)(n0 + r0) * K + e0;
  const u16* b1 = Bt + (size_t)(n0 + r1) * K + e1;
  u16* lA0 = &As[c0 * 8]; u16* lA1 = &As[c1 * 8];
  u16* lB0 = &Bs[c0 * 8]; u16* lB1 = &Bs[c1 * 8];

  for (int k0 = 0; k0 < K; k0 += 32) {
    __syncthreads();
    load_lds16(a0 + k0, lA0);
    load_lds16(a1 + k0, lA1);
    load_lds16(b0 + k0, lB0);
    load_lds16(b1 + k0, lB1);
    __syncthreads();
    u16x8 af[4], bf[4];
    #pragma unroll
    for (int mi = 0; mi < 4; mi++)
      af[mi] = *(const u16x8*)&As[(wm + mi * 16 + ql) * 32 + kg * 8];
    #pragma unroll
    for (int ni = 0; ni < 4; ni++)
      bf[ni] = *(const u16x8*)&Bs[(wn + ni * 16 + ql) * 32 + kg * 8];
    #pragma unroll
    for (int mi = 0; mi < 4; mi++)
      #pragma unroll
      for (int ni = 0; ni < 4; ni++)
        acc[mi][ni] = mfma16(af[mi], bf[ni], acc[mi][ni]);
  }

  #pragma unroll
  for (int mi = 0; mi < 4; mi++) {
    #pragma unroll
    for (int ni = 0; ni < 4; ni++) {
      int row = m0 + wm + mi * 16 + kg * 4;
      int col = n0 + wn + ni * 16 + ql;
      #pragma unroll
      for (int r = 0; r < 4; r++) {
        if constexpr (OUT_BF16)
          Cb[(size_t)(row + r) * N + col] = f2bf(acc[mi][ni][r]);
        else
          Cf[(size_t)(row + r) * N + col] = acc[mi][ni][r];
      }
    }
  }
}

// ---------------- flash attention, causal, GQA (g=4) ----------------
// grid (L/64, 32 heads), 256 thr = 4 waves; wave owns 16 q rows. KVBLK=32.
// Swapped QK^T: D[s][q] = mfma(Kfrag, Qfrag) -> softmax lane-local per q=l&15.
__global__ __launch_bounds__(256)
void attn_k(const u16* __restrict__ qr, const u16* __restrict__ kr,
            const u16* __restrict__ vb, u16* __restrict__ out, int L) {
  __shared__ alignas(16) u16 Vt[128 * 32];       // [d][s]
  __shared__ alignas(16) u16 Plds[4][16 * 32];   // per-wave [q][s]
  const int tid = threadIdx.x;
  const int lane = tid & 63, wave = tid >> 6;
  const int ql = lane & 15, kg = lane >> 4;
  const int h = blockIdx.y, hk = h >> 2;
  const int q0 = blockIdx.x * 64;
  const int qw = q0 + wave * 16;
  const float scale = 0.08838834764831845f;

  // hoist Q fragments (B-operand: n = l&15 = q, k = kg*8+i over d-slice kk*32)
  u16x8 qf[4];
  const u16* qbase = qr + ((size_t)(qw + ql) * 32 + h) * 128;
  #pragma unroll
  for (int kk = 0; kk < 4; kk++)
    qf[kk] = *(const u16x8*)(qbase + kk * 32 + kg * 8);

  f32x4 acc[8] = {};
  float m_run = -3e38f, l_run = 0.f;

  for (int s0 = 0; s0 < q0 + 64; s0 += 32) {
    __syncthreads();  // (A) prev-iter Vt/Plds reads done
    // stage Vt[d][s] transposed from vb[s][d]
    {
      int sl2 = (tid & 15) * 2;
      int d0 = (tid >> 4) * 8;
      u16x8 v0 = *(const u16x8*)(vb + ((size_t)(s0 + sl2) * 8 + hk) * 128 + d0);
      u16x8 v1 = *(const u16x8*)(vb + ((size_t)(s0 + sl2 + 1) * 8 + hk) * 128 + d0);
      #pragma unroll
      for (int e = 0; e < 8; e++) {
        ushort2 w; w.x = v0[e]; w.y = v1[e];
        *(ushort2*)&Vt[(d0 + e) * 32 + sl2] = w;
      }
    }
    __syncthreads();  // (B) Vt visible

    const bool active = (s0 <= qw + 15);  // wave-uniform; skipped tiles are fully masked
    if (active) {
      // scores: D[s][q], A = K rows, B = Q
      f32x4 sc[2] = {};
      #pragma unroll
      for (int sb = 0; sb < 2; sb++)
        #pragma unroll
        for (int kk = 0; kk < 4; kk++) {
          u16x8 kf = *(const u16x8*)(kr + ((size_t)(s0 + sb * 16 + ql) * 8 + hk) * 128 + kk * 32 + kg * 8);
          sc[sb] = mfma16(kf, qf[kk], sc[sb]);
        }
      // lane holds S[s0+sb*16+kg*4+r][qw+ql]
      float p[2][4];
      float mt = -3e38f;
      const int qg = qw + ql;
      #pragma unroll
      for (int sb = 0; sb < 2; sb++)
        #pragma unroll
        for (int r = 0; r < 4; r++) {
          int s = s0 + sb * 16 + kg * 4 + r;
          float v = sc[sb][r] * scale;
          v = (s > qg) ? -3e38f : v;
          p[sb][r] = v;
          mt = fmaxf(mt, v);
        }
      mt = fmaxf(mt, __shfl_xor(mt, 16, 64));
      mt = fmaxf(mt, __shfl_xor(mt, 32, 64));
      float m_new = fmaxf(m_run, mt);
      float fco = expf(m_run - m_new);
      float rs = 0.f;
      #pragma unroll
      for (int sb = 0; sb < 2; sb++)
        #pragma unroll
        for (int r = 0; r < 4; r++) {
          float e = expf(p[sb][r] - m_new);
          p[sb][r] = e;
          rs += e;
        }
      rs += __shfl_xor(rs, 16, 64);
      rs += __shfl_xor(rs, 32, 64);
      l_run = l_run * fco + rs;
      m_run = m_new;
      // rescale acc rows (row q' = kg*4+r; factor held by lanes with l&15==q')
      float fr[4];
      #pragma unroll
      for (int r = 0; r < 4; r++) fr[r] = __shfl(fco, (lane & 48) | (kg * 4 + r), 64);
      #pragma unroll
      for (int db = 0; db < 8; db++)
        #pragma unroll
        for (int r = 0; r < 4; r++) acc[db][r] *= fr[r];
      // write P[q][s] bf16 to per-wave LDS (4 consecutive s per write)
      #pragma unroll
      for (int sb = 0; sb < 2; sb++) {
        ushort4 pk;
        pk.x = f2bf(p[sb][0]); pk.y = f2bf(p[sb][1]);
        pk.z = f2bf(p[sb][2]); pk.w = f2bf(p[sb][3]);
        *(ushort4*)&Plds[wave][ql * 32 + sb * 16 + kg * 4] = pk;
      }
    }
    __syncthreads();  // (C) Plds visible (uniform barrier)
    if (active) {
      // PV: A = P[q][s] (m=l&15=q, k=kg*8+i=s), B = Vt[d][s] (n=l&15 -> d)
      u16x8 pf = *(const u16x8*)&Plds[wave][ql * 32 + kg * 8];
      #pragma unroll
      for (int db = 0; db < 8; db++) {
        u16x8 vf = *(const u16x8*)&Vt[(db * 16 + ql) * 32 + kg * 8];
        acc[db] = mfma16(pf, vf, acc[db]);
      }
    }
  }

  float linv[4];
  #pragma unroll
  for (int r = 0; r < 4; r++)
    linv[r] = 1.f / __shfl(l_run, (lane & 48) | (kg * 4 + r), 64);
  #pragma unroll
  for (int db = 0; db < 8; db++) {
    int d = db * 16 + ql;
    #pragma unroll
    for (int r = 0; r < 4; r++) {
      int q = qw + kg * 4 + r;
      out[((size_t)q * 32 + h) * 128 + d] = f2bf(acc[db][r] * linv[r]);
    }
  }
}

// ---------------- launcher ----------------
extern "C" void kernel_launch(void* const* d_in, const int* in_sizes, int n_in,
                              void* d_out, int out_size, void* d_ws, size_t ws_size,
                              hipStream_t stream) {
  const float* x  = (const float*)d_in[0];
  const float* Wq = (const float*)d_in[1];
  const float* Wk = (const float*)d_in[2];
  const float* Wv = (const float*)d_in[3];
  const float* Wo = (const float*)d_in[4];
  const int* start = (const int*)d_in[5];

  const int L = 2048, HID = 4096, NH = 32, NKV = 8;
  const int NQ = 4096, NKVD = 1024;

  char* ws = (char*)d_ws;
  size_t off = 0;
  auto alloc = [&](size_t bytes) {
    void* p = ws + off;
    off += (bytes + 255) & ~(size_t)255;
    return p;
  };
  u16* x_b   = (u16*)alloc((size_t)L * HID * 2);
  u16* Wq_t  = (u16*)alloc((size_t)NQ * HID * 2);
  u16* Wk_t  = (u16*)alloc((size_t)NKVD * HID * 2);
  u16* Wv_t  = (u16*)alloc((size_t)NKVD * HID * 2);
  u16* Wo_t  = (u16*)alloc((size_t)HID * NQ * 2);
  float* kf  = (float*)alloc((size_t)L * NKVD * 4);
  u16* q_r   = (u16*)alloc((size_t)L * NQ * 2);
  u16* k_r   = (u16*)alloc((size_t)L * NKVD * 2);
  u16* v_b   = (u16*)alloc((size_t)L * NKVD * 2);
  float2* tab = (float2*)alloc((size_t)L * 64 * sizeof(float2));
  float* qf = (float*)d_out;   // d_out doubles as Q-f32 scratch; rewritten by final GEMM
  u16* attn_b = Wq_t;          // reuse Wq^T region after Q GEMM

  // conversions / transposes / table
  cvt_f32_bf16<<<(L * HID / 4 + 255) / 256, 256, 0, stream>>>(x, x_b, L * HID / 4);
  transpose_cvt<<<dim3(HID / 32, NQ / 32), 256, 0, stream>>>(Wq, Wq_t, HID, NQ);
  transpose_cvt<<<dim3(HID / 32, NKVD / 32), 256, 0, stream>>>(Wk, Wk_t, HID, NKVD);
  transpose_cvt<<<dim3(HID / 32, NKVD / 32), 256, 0, stream>>>(Wv, Wv_t, HID, NKVD);
  transpose_cvt<<<dim3(NQ / 32, HID / 32), 256, 0, stream>>>(Wo, Wo_t, NQ, HID);
  rope_table_k<<<(L * 64 + 255) / 256, 256, 0, stream>>>(tab, start, L);

  // QKV projections
  gemm_bt<false><<<dim3(L / 128, NQ / 128), 256, 0, stream>>>(x_b, Wq_t, qf, nullptr, L, NQ, HID);
  gemm_bt<false><<<dim3(L / 128, NKVD / 128), 256, 0, stream>>>(x_b, Wk_t, kf, nullptr, L, NKVD, HID);
  gemm_bt<true><<<dim3(L / 128, NKVD / 128), 256, 0, stream>>>(x_b, Wv_t, nullptr, v_b, L, NKVD, HID);

  // RoPE
  rope_apply_k<<<(L * NH * 64 + 255) / 256, 256, 0, stream>>>(qf, q_r, tab, L, NH);
  rope_apply_k<<<(L * NKV * 64 + 255) / 256, 256, 0, stream>>>(kf, k_r, tab, L, NKV);

  // attention
  attn_k<<<dim3(L / 64, NH), 256, 0, stream>>>(q_r, k_r, v_b, attn_b, L);

  // output projection (rewrites all of d_out)
  gemm_bt<false><<<dim3(L / 128, HID / 128), 256, 0, stream>>>(attn_b, Wo_t, (float*)d_out, nullptr, L, HID, NQ);
}

// Round 2
// 677.969 us; speedup vs baseline: 1.1708x; 1.1708x over previous
//
#include <hip/hip_runtime.h>

typedef unsigned short u16;
typedef float f32x4 __attribute__((ext_vector_type(4)));
typedef __bf16 bf16x8 __attribute__((ext_vector_type(8)));
typedef u16 u16x8 __attribute__((ext_vector_type(8)));

static __device__ __forceinline__ u16 f2bf(float f) {
  union { float f; unsigned u; } v; v.f = f;
  unsigned r = v.u + 0x7fffu + ((v.u >> 16) & 1u);  // RNE
  return (u16)(r >> 16);
}

static __device__ __forceinline__ f32x4 mfma16(u16x8 a, u16x8 b, f32x4 c) {
  return __builtin_amdgcn_mfma_f32_16x16x32_bf16(
      __builtin_bit_cast(bf16x8, a), __builtin_bit_cast(bf16x8, b), c, 0, 0, 0);
}

static __device__ __forceinline__ void load_lds16(const void* g, void* l) {
  __builtin_amdgcn_global_load_lds(
      (const __attribute__((address_space(1))) void*)g,
      (__attribute__((address_space(3))) void*)l, 16, 0, 0);
}

// ---------------- elementwise f32 -> bf16 ----------------
__global__ void cvt_f32_bf16(const float* __restrict__ in, u16* __restrict__ out, int n4) {
  int i = blockIdx.x * blockDim.x + threadIdx.x;
  if (i >= n4) return;
  float4 v = ((const float4*)in)[i];
  ushort4 o;
  o.x = f2bf(v.x); o.y = f2bf(v.y); o.z = f2bf(v.z); o.w = f2bf(v.w);
  ((ushort4*)out)[i] = o;
}

// ---------------- transpose + convert: W[K][N] f32 -> Wt[N][K] bf16 ----------------
__global__ __launch_bounds__(256)
void transpose_cvt(const float* __restrict__ W, u16* __restrict__ Wt, int K, int N) {
  __shared__ float tile[32][33];
  int tx = threadIdx.x & 31, ty = threadIdx.x >> 5;
  int k0 = blockIdx.x * 32, n0 = blockIdx.y * 32;
  #pragma unroll
  for (int i = ty; i < 32; i += 8)
    tile[i][tx] = W[(size_t)(k0 + i) * N + (n0 + tx)];
  __syncthreads();
  #pragma unroll
  for (int i = ty; i < 32; i += 8)
    Wt[(size_t)(n0 + i) * K + (k0 + tx)] = f2bf(tile[tx][i]);
}

// ---------------- RoPE cos/sin table: [L][64] float2 ----------------
__global__ void rope_table_k(float2* __restrict__ tab, const int* __restrict__ start, int L) {
  int i = blockIdx.x * blockDim.x + threadIdx.x;
  if (i >= L * 64) return;
  int p = i >> 6, j = i & 63;
  float inv = powf(10000.0f, -(float)j / 64.0f);
  float ang = (float)(p + start[0]) * inv;
  tab[i] = make_float2(cosf(ang), sinf(ang));
}

// ---------------- RoPE apply: q f32 [L][H][128] -> bf16 (rotate-half), * scale ----------------
__global__ void rope_apply_k(const float* __restrict__ qin, u16* __restrict__ qout,
                             const float2* __restrict__ tab, int L, int H, float scale) {
  int i = blockIdx.x * blockDim.x + threadIdx.x;
  if (i >= L * H * 64) return;
  int j = i & 63;
  int h = (i >> 6) % H;
  int p = i / (64 * H);
  size_t base = ((size_t)p * H + h) * 128;
  float2 cs = tab[p * 64 + j];
  float a = qin[base + j], b = qin[base + j + 64];
  qout[base + j]      = f2bf((a * cs.x - b * cs.y) * scale);
  qout[base + j + 64] = f2bf((a * cs.y + b * cs.x) * scale);
}

// ---------------- GEMM: C[M][N] = A[M][K](bf16) @ Bt[N][K](bf16) ----------------
template<bool OUT_BF16>
__global__ __launch_bounds__(256)
void gemm_bt(const u16* __restrict__ A, const u16* __restrict__ Bt,
             float* __restrict__ Cf, u16* __restrict__ Cb, int M, int N, int K) {
  __shared__ alignas(16) u16 As[128 * 32];
  __shared__ alignas(16) u16 Bs[128 * 32];
  const int tid = threadIdx.x;
  const int lane = tid & 63, wave = tid >> 6;
  const int ql = lane & 15, kg = lane >> 4;
  const int m0 = blockIdx.x * 128, n0 = blockIdx.y * 128;
  const int wm = (wave >> 1) * 64, wn = (wave & 1) * 64;

  f32x4 acc[4][4] = {};

  const int c0 = tid, c1 = 256 + tid;
  const int r0 = c0 >> 2, e0 = (c0 & 3) * 8;
  const int r1 = c1 >> 2, e1 = (c1 & 3) * 8;
  const u16* a0 = A + (size_t)(m0 + r0) * K + e0;
  const u16* a1 = A + (size_t)(m0 + r1) * K + e1;
  const u16* b0 = Bt + (size_t)(n0 + r0) * K + e0;
  const u16* b1 = Bt + (size_t)(n0 + r1) * K + e1;
  u16* lA0 = &As[c0 * 8]; u16* lA1 = &As[c1 * 8];
  u16* lB0 = &Bs[c0 * 8]; u16* lB1 = &Bs[c1 * 8];

  for (int k0 = 0; k0 < K; k0 += 32) {
    __syncthreads();
    load_lds16(a0 + k0, lA0);
    load_lds16(a1 + k0, lA1);
    load_lds16(b0 + k0, lB0);
    load_lds16(b1 + k0, lB1);
    __syncthreads();
    u16x8 af[4], bf[4];
    #pragma unroll
    for (int mi = 0; mi < 4; mi++)
      af[mi] = *(const u16x8*)&As[(wm + mi * 16 + ql) * 32 + kg * 8];
    #pragma unroll
    for (int ni = 0; ni < 4; ni++)
      bf[ni] = *(const u16x8*)&Bs[(wn + ni * 16 + ql) * 32 + kg * 8];
    #pragma unroll
    for (int mi = 0; mi < 4; mi++)
      #pragma unroll
      for (int ni = 0; ni < 4; ni++)
        acc[mi][ni] = mfma16(af[mi], bf[ni], acc[mi][ni]);
  }

  #pragma unroll
  for (int mi = 0; mi < 4; mi++) {
    #pragma unroll
    for (int ni = 0; ni < 4; ni++) {
      int row = m0 + wm + mi * 16 + kg * 4;
      int col = n0 + wn + ni * 16 + ql;
      #pragma unroll
      for (int r = 0; r < 4; r++) {
        if constexpr (OUT_BF16)
          Cb[(size_t)(row + r) * N + col] = f2bf(acc[mi][ni][r]);
        else
          Cf[(size_t)(row + r) * N + col] = acc[mi][ni][r];
      }
    }
  }
}

// ---------------- flash attention, causal, GQA (g=4) ----------------
// grid (16, 32 heads), 256 thr = 4 waves; block handles q-tiles {bx, 31-bx}
// (wrap-pairing: every block does exactly 33 KV-steps -> balanced).
// KVBLK=64, one barrier per step, Vt double-buffered, V prefetched into regs.
// Swapped QK^T: D[s][q] = mfma(Kfrag, Qfrag) -> softmax lane-local per q=l&15.
// Q is pre-scaled by 1/sqrt(d) at RoPE time. Defer-max with THR=8 (T13).
__global__ __launch_bounds__(256)
void attn_k(const u16* __restrict__ qr, const u16* __restrict__ kr,
            const u16* __restrict__ vb, u16* __restrict__ out, int L) {
  __shared__ alignas(16) u16 Vt[2][128][72];    // [buf][d][s+pad]; 144B rows (16B-mult)
  __shared__ alignas(16) u16 Plds[4][16][72];   // per-wave [q][s+pad]
  const int tid = threadIdx.x;
  const int lane = tid & 63, wave = tid >> 6;
  const int ql = lane & 15, kg = lane >> 4;
  const int h = blockIdx.y, hk = h >> 2;
  const float LOG2E = 1.44269504089f;

  // V staging: thread covers s in [sl4, sl4+4), d in [d0s, d0s+8)
  const int sl4 = (tid & 15) * 4;
  const int d0s = (tid >> 4) * 8;
  const u16* vbase = vb + (size_t)hk * 128 + d0s;

  int cur = 0;
  #pragma unroll 1
  for (int half_idx = 0; half_idx < 2; half_idx++) {
    const int tile = half_idx ? (31 - (int)blockIdx.x) : (int)blockIdx.x;
    const int q0 = tile * 64;
    const int qw = q0 + wave * 16;
    const int nsteps = tile + 1;

    // hoist Q fragments (B-operand: n=l&15=q, k over d)
    u16x8 qf[4];
    const u16* qbase = qr + ((size_t)(qw + ql) * 32 + h) * 128;
    #pragma unroll
    for (int kk = 0; kk < 4; kk++)
      qf[kk] = *(const u16x8*)(qbase + kk * 32 + kg * 8);

    f32x4 acc[8] = {};
    float m_run = -3e38f, l_run = 0.f;

    // prologue: V regs for step 0
    u16x8 vreg[4];
    #pragma unroll
    for (int j = 0; j < 4; j++)
      vreg[j] = *(const u16x8*)(vbase + (size_t)(sl4 + j) * 1024);

    #pragma unroll 1
    for (int t = 0; t < nsteps; t++) {
      const int s0 = t * 64;
      // (1) commit V tile t into Vt[cur] (transposed [d][s])
      #pragma unroll
      for (int e = 0; e < 8; e++) {
        ushort4 w;
        w.x = vreg[0][e]; w.y = vreg[1][e]; w.z = vreg[2][e]; w.w = vreg[3][e];
        *(ushort4*)&Vt[cur][d0s + e][sl4] = w;
      }
      __syncthreads();  // the ONLY barrier per step
      // (2) prefetch V tile t+1 into regs (latency hides under (3)-(6))
      if (t + 1 < nsteps) {
        #pragma unroll
        for (int j = 0; j < 4; j++)
          vreg[j] = *(const u16x8*)(vbase + (size_t)((t + 1) * 64 + sl4 + j) * 1024);
      }
      // (3) QK^T: D[s][q], A = K rows (global/L2), B = Q
      f32x4 sc[4] = {};
      #pragma unroll
      for (int sb = 0; sb < 4; sb++) {
        const u16* krow = kr + ((size_t)(s0 + sb * 16 + ql) * 8 + hk) * 128 + kg * 8;
        #pragma unroll
        for (int kk = 0; kk < 4; kk++) {
          u16x8 kf = *(const u16x8*)(krow + kk * 32);
          sc[sb] = mfma16(kf, qf[kk], sc[sb]);
        }
      }
      // (4) online softmax with defer-max (THR=8)
      const int qg = qw + ql;
      float p[4][4];
      float mt = -3e38f;
      #pragma unroll
      for (int sb = 0; sb < 4; sb++)
        #pragma unroll
        for (int r = 0; r < 4; r++) {
          int s = s0 + sb * 16 + kg * 4 + r;
          float v = (s > qg) ? -3e38f : sc[sb][r];
          p[sb][r] = v;
          mt = fmaxf(mt, v);
        }
      mt = fmaxf(mt, __shfl_xor(mt, 16, 64));
      mt = fmaxf(mt, __shfl_xor(mt, 32, 64));
      if (!__all(mt - m_run <= 8.f)) {
        float m_new = fmaxf(m_run, mt);
        float fco = exp2f((m_run - m_new) * LOG2E);
        float fr[4];
        #pragma unroll
        for (int r = 0; r < 4; r++) fr[r] = __shfl(fco, (lane & 48) | (kg * 4 + r), 64);
        #pragma unroll
        for (int db = 0; db < 8; db++)
          #pragma unroll
          for (int r = 0; r < 4; r++) acc[db][r] *= fr[r];
        l_run *= fco;
        m_run = m_new;
      }
      float rs = 0.f;
      #pragma unroll
      for (int sb = 0; sb < 4; sb++)
        #pragma unroll
        for (int r = 0; r < 4; r++) {
          float e = exp2f((p[sb][r] - m_run) * LOG2E);
          p[sb][r] = e;
          rs += e;
        }
      rs += __shfl_xor(rs, 16, 64);
      rs += __shfl_xor(rs, 32, 64);
      l_run += rs;
      // (5) P -> per-wave LDS (wave-local: no block barrier needed)
      #pragma unroll
      for (int sb = 0; sb < 4; sb++) {
        ushort4 pk;
        pk.x = f2bf(p[sb][0]); pk.y = f2bf(p[sb][1]);
        pk.z = f2bf(p[sb][2]); pk.w = f2bf(p[sb][3]);
        *(ushort4*)&Plds[wave][ql][sb * 16 + kg * 4] = pk;
      }
      // (6) PV: A = P[q][s], B = Vt[d][s]; K=64 via two halves
      #pragma unroll
      for (int hf = 0; hf < 2; hf++) {
        u16x8 pf = *(const u16x8*)&Plds[wave][ql][hf * 32 + kg * 8];
        #pragma unroll
        for (int db = 0; db < 8; db++) {
          u16x8 vf = *(const u16x8*)&Vt[cur][db * 16 + ql][hf * 32 + kg * 8];
          acc[db] = mfma16(pf, vf, acc[db]);
        }
      }
      cur ^= 1;
    }

    // epilogue for this q-tile
    float linv[4];
    #pragma unroll
    for (int r = 0; r < 4; r++)
      linv[r] = 1.f / __shfl(l_run, (lane & 48) | (kg * 4 + r), 64);
    #pragma unroll
    for (int db = 0; db < 8; db++) {
      int d = db * 16 + ql;
      #pragma unroll
      for (int r = 0; r < 4; r++) {
        int q = qw + kg * 4 + r;
        out[((size_t)q * 32 + h) * 128 + d] = f2bf(acc[db][r] * linv[r]);
      }
    }
  }
}

// ---------------- launcher ----------------
extern "C" void kernel_launch(void* const* d_in, const int* in_sizes, int n_in,
                              void* d_out, int out_size, void* d_ws, size_t ws_size,
                              hipStream_t stream) {
  const float* x  = (const float*)d_in[0];
  const float* Wq = (const float*)d_in[1];
  const float* Wk = (const float*)d_in[2];
  const float* Wv = (const float*)d_in[3];
  const float* Wo = (const float*)d_in[4];
  const int* start = (const int*)d_in[5];

  const int L = 2048, HID = 4096, NH = 32, NKV = 8;
  const int NQ = 4096, NKVD = 1024;

  char* ws = (char*)d_ws;
  size_t off = 0;
  auto alloc = [&](size_t bytes) {
    void* p = ws + off;
    off += (bytes + 255) & ~(size_t)255;
    return p;
  };
  u16* x_b   = (u16*)alloc((size_t)L * HID * 2);
  u16* Wq_t  = (u16*)alloc((size_t)NQ * HID * 2);
  u16* Wk_t  = (u16*)alloc((size_t)NKVD * HID * 2);
  u16* Wv_t  = (u16*)alloc((size_t)NKVD * HID * 2);
  u16* Wo_t  = (u16*)alloc((size_t)HID * NQ * 2);
  float* kf  = (float*)alloc((size_t)L * NKVD * 4);
  u16* q_r   = (u16*)alloc((size_t)L * NQ * 2);
  u16* k_r   = (u16*)alloc((size_t)L * NKVD * 2);
  u16* v_b   = (u16*)alloc((size_t)L * NKVD * 2);
  float2* tab = (float2*)alloc((size_t)L * 64 * sizeof(float2));
  float* qf = (float*)d_out;   // d_out doubles as Q-f32 scratch; rewritten by final GEMM
  u16* attn_b = Wq_t;          // reuse Wq^T region after Q GEMM

  const float scale = 0.08838834764831845f;  // 1/sqrt(128)

  // conversions / transposes / table
  cvt_f32_bf16<<<(L * HID / 4 + 255) / 256, 256, 0, stream>>>(x, x_b, L * HID / 4);
  transpose_cvt<<<dim3(HID / 32, NQ / 32), 256, 0, stream>>>(Wq, Wq_t, HID, NQ);
  transpose_cvt<<<dim3(HID / 32, NKVD / 32), 256, 0, stream>>>(Wk, Wk_t, HID, NKVD);
  transpose_cvt<<<dim3(HID / 32, NKVD / 32), 256, 0, stream>>>(Wv, Wv_t, HID, NKVD);
  transpose_cvt<<<dim3(NQ / 32, HID / 32), 256, 0, stream>>>(Wo, Wo_t, NQ, HID);
  rope_table_k<<<(L * 64 + 255) / 256, 256, 0, stream>>>(tab, start, L);

  // QKV projections
  gemm_bt<false><<<dim3(L / 128, NQ / 128), 256, 0, stream>>>(x_b, Wq_t, qf, nullptr, L, NQ, HID);
  gemm_bt<false><<<dim3(L / 128, NKVD / 128), 256, 0, stream>>>(x_b, Wk_t, kf, nullptr, L, NKVD, HID);
  gemm_bt<true><<<dim3(L / 128, NKVD / 128), 256, 0, stream>>>(x_b, Wv_t, nullptr, v_b, L, NKVD, HID);

  // RoPE (Q pre-scaled by 1/sqrt(d))
  rope_apply_k<<<(L * NH * 64 + 255) / 256, 256, 0, stream>>>(qf, q_r, tab, L, NH, scale);
  rope_apply_k<<<(L * NKV * 64 + 255) / 256, 256, 0, stream>>>(kf, k_r, tab, L, NKV, 1.0f);

  // attention (wrap-paired causal tiles)
  attn_k<<<dim3(16, NH), 256, 0, stream>>>(q_r, k_r, v_b, attn_b, L);

  // output projection (rewrites all of d_out)
  gemm_bt<false><<<dim3(L / 128, HID / 128), 256, 0, stream>>>(attn_b, Wo_t, (float*)d_out, nullptr, L, HID, NQ);
}

// Round 3
// 516.106 us; speedup vs baseline: 1.5380x; 1.3136x over previous
//
#include <hip/hip_runtime.h>

typedef unsigned short u16;
typedef float f32x4 __attribute__((ext_vector_type(4)));
typedef __bf16 bf16x8 __attribute__((ext_vector_type(8)));
typedef u16 u16x8 __attribute__((ext_vector_type(8)));

static __device__ __forceinline__ u16 f2bf(float f) {
  union { float f; unsigned u; } v; v.f = f;
  unsigned r = v.u + 0x7fffu + ((v.u >> 16) & 1u);  // RNE
  return (u16)(r >> 16);
}
static __device__ __forceinline__ float bf2f(u16 x) {
  union { unsigned u; float f; } v; v.u = (unsigned)x << 16; return v.f;
}

static __device__ __forceinline__ f32x4 mfma16(u16x8 a, u16x8 b, f32x4 c) {
  return __builtin_amdgcn_mfma_f32_16x16x32_bf16(
      __builtin_bit_cast(bf16x8, a), __builtin_bit_cast(bf16x8, b), c, 0, 0, 0);
}

static __device__ __forceinline__ void load_lds16(const void* g, void* l) {
  __builtin_amdgcn_global_load_lds(
      (const __attribute__((address_space(1))) void*)g,
      (__attribute__((address_space(3))) void*)l, 16, 0, 0);
}

// ---------------- elementwise f32 -> bf16 ----------------
__global__ void cvt_f32_bf16(const float* __restrict__ in, u16* __restrict__ out, int n4) {
  int i = blockIdx.x * blockDim.x + threadIdx.x;
  if (i >= n4) return;
  float4 v = ((const float4*)in)[i];
  ushort4 o;
  o.x = f2bf(v.x); o.y = f2bf(v.y); o.z = f2bf(v.z); o.w = f2bf(v.w);
  ((ushort4*)out)[i] = o;
}

// ---------------- transpose + convert: W[K][N] f32 -> Wt[N][K] bf16 ----------------
__global__ __launch_bounds__(256)
void transpose_cvt(const float* __restrict__ W, u16* __restrict__ Wt, int K, int N) {
  __shared__ float tile[32][33];
  int tx = threadIdx.x & 31, ty = threadIdx.x >> 5;
  int k0 = blockIdx.x * 32, n0 = blockIdx.y * 32;
  #pragma unroll
  for (int i = ty; i < 32; i += 8)
    tile[i][tx] = W[(size_t)(k0 + i) * N + (n0 + tx)];
  __syncthreads();
  #pragma unroll
  for (int i = ty; i < 32; i += 8)
    Wt[(size_t)(n0 + i) * K + (k0 + tx)] = f2bf(tile[tx][i]);
}

// ---------------- RoPE cos/sin table: [L][64] float2 ----------------
__global__ void rope_table_k(float2* __restrict__ tab, const int* __restrict__ start, int L) {
  int i = blockIdx.x * blockDim.x + threadIdx.x;
  if (i >= L * 64) return;
  int p = i >> 6, j = i & 63;
  float inv = powf(10000.0f, -(float)j / 64.0f);
  float ang = (float)(p + start[0]) * inv;
  tab[i] = make_float2(cosf(ang), sinf(ang));
}

// ---------------- RoPE apply (bf16 in, strided) -> bf16 [L][H][128], * scale ----------------
__global__ void rope_apply_b(const u16* __restrict__ in, int istride, int icol,
                             u16* __restrict__ outp, const float2* __restrict__ tab,
                             int total, int H, float scale) {
  int i = blockIdx.x * blockDim.x + threadIdx.x;  // total = L*H*8
  if (i >= total) return;
  int j8 = (i & 7) * 8;
  int h = (i >> 3) % H;
  int p = i / (8 * H);
  const u16* base = in + (size_t)p * istride + icol + h * 128;
  u16x8 a = *(const u16x8*)(base + j8);
  u16x8 b = *(const u16x8*)(base + j8 + 64);
  u16x8 o1, o2;
  #pragma unroll
  for (int e = 0; e < 8; e++) {
    float2 cs = tab[p * 64 + j8 + e];
    float av = bf2f(a[e]), bv = bf2f(b[e]);
    o1[e] = f2bf((av * cs.x - bv * cs.y) * scale);
    o2[e] = f2bf((av * cs.y + bv * cs.x) * scale);
  }
  u16* ob = outp + ((size_t)p * H + h) * 128 + j8;
  *(u16x8*)ob = o1;
  *(u16x8*)(ob + 64) = o2;
}

// ---------------- GEMM: C[M][N] = A[M][K](bf16) @ Bt[N][K](bf16) ----------------
template<bool OUT_BF16>
__global__ __launch_bounds__(256)
void gemm_bt(const u16* __restrict__ A, const u16* __restrict__ Bt,
             float* __restrict__ Cf, u16* __restrict__ Cb, int M, int N, int K) {
  __shared__ alignas(16) u16 As[128 * 32];
  __shared__ alignas(16) u16 Bs[128 * 32];
  const int tid = threadIdx.x;
  const int lane = tid & 63, wave = tid >> 6;
  const int ql = lane & 15, kg = lane >> 4;
  const int m0 = blockIdx.x * 128, n0 = blockIdx.y * 128;
  const int wm = (wave >> 1) * 64, wn = (wave & 1) * 64;

  f32x4 acc[4][4] = {};

  const int c0 = tid, c1 = 256 + tid;
  const int r0 = c0 >> 2, e0 = (c0 & 3) * 8;
  const int r1 = c1 >> 2, e1 = (c1 & 3) * 8;
  const u16* a0 = A + (size_t)(m0 + r0) * K + e0;
  const u16* a1 = A + (size_t)(m0 + r1) * K + e1;
  const u16* b0 = Bt + (size_t)(n0 + r0) * K + e0;
  const u16* b1 = Bt + (size_t)(n0 + r1) * K + e1;
  u16* lA0 = &As[c0 * 8]; u16* lA1 = &As[c1 * 8];
  u16* lB0 = &Bs[c0 * 8]; u16* lB1 = &Bs[c1 * 8];

  for (int k0 = 0; k0 < K; k0 += 32) {
    __syncthreads();
    load_lds16(a0 + k0, lA0);
    load_lds16(a1 + k0, lA1);
    load_lds16(b0 + k0, lB0);
    load_lds16(b1 + k0, lB1);
    __syncthreads();
    u16x8 af[4], bfr[4];
    #pragma unroll
    for (int mi = 0; mi < 4; mi++)
      af[mi] = *(const u16x8*)&As[(wm + mi * 16 + ql) * 32 + kg * 8];
    #pragma unroll
    for (int ni = 0; ni < 4; ni++)
      bfr[ni] = *(const u16x8*)&Bs[(wn + ni * 16 + ql) * 32 + kg * 8];
    #pragma unroll
    for (int mi = 0; mi < 4; mi++)
      #pragma unroll
      for (int ni = 0; ni < 4; ni++)
        acc[mi][ni] = mfma16(af[mi], bfr[ni], acc[mi][ni]);
  }

  #pragma unroll
  for (int mi = 0; mi < 4; mi++) {
    #pragma unroll
    for (int ni = 0; ni < 4; ni++) {
      int row = m0 + wm + mi * 16 + kg * 4;
      int col = n0 + wn + ni * 16 + ql;
      #pragma unroll
      for (int r = 0; r < 4; r++) {
        if constexpr (OUT_BF16)
          Cb[(size_t)(row + r) * N + col] = f2bf(acc[mi][ni][r]);
        else
          Cf[(size_t)(row + r) * N + col] = acc[mi][ni][r];
      }
    }
  }
}

// ---------------- flash attention, causal, GQA (g=4) ----------------
// grid (16, 32 heads), 256 thr = 4 waves; block handles q-tiles {bx, 31-bx}.
// KVBLK=64, one barrier/step, Vt double-buffered; K AND V prefetched into regs
// (issued after consumption, ~full step to complete). Swapped QK^T; softmax in
// exp2 domain (Q pre-scaled by log2e/sqrt(d)); defer-max THR=11.5 (=8 nat).
__global__ __launch_bounds__(256)
void attn_k(const u16* __restrict__ qr, const u16* __restrict__ kr,
            const u16* __restrict__ qkv, u16* __restrict__ out) {
  __shared__ alignas(16) u16 Vt[2][128][72];
  __shared__ alignas(16) u16 Plds[4][16][72];
  const int tid = threadIdx.x;
  const int lane = tid & 63, wave = tid >> 6;
  const int ql = lane & 15, kg = lane >> 4;
  const int h = blockIdx.y, hk = h >> 2;

  // V staging: thread covers s in [sl4,sl4+4), d in [d0s,d0s+8); V lives in
  // fused qkv buffer at col 5120 + hk*128, row stride 6144.
  const int sl4 = (tid & 15) * 4;
  const int d0s = (tid >> 4) * 8;
  const u16* vbase = qkv + 5120 + (size_t)hk * 128 + d0s;
  // K fragment base for this lane
  const u16* kptr = kr + (size_t)hk * 128 + (size_t)ql * 1024 + kg * 8;

  int cur = 0;
  #pragma unroll 1
  for (int half_idx = 0; half_idx < 2; half_idx++) {
    const int tile = half_idx ? (31 - (int)blockIdx.x) : (int)blockIdx.x;
    const int q0 = tile * 64;
    const int qw = q0 + wave * 16;
    const int nsteps = tile + 1;

    u16x8 qf[4];
    const u16* qbase = qr + ((size_t)(qw + ql) * 32 + h) * 128;
    #pragma unroll
    for (int kk = 0; kk < 4; kk++)
      qf[kk] = *(const u16x8*)(qbase + kk * 32 + kg * 8);

    f32x4 acc[8] = {};
    float m_run = -3e38f, l_run = 0.f;

    // prologue: V and K regs for step 0
    u16x8 vreg[4];
    #pragma unroll
    for (int j = 0; j < 4; j++)
      vreg[j] = *(const u16x8*)(vbase + (size_t)(sl4 + j) * 6144);
    u16x8 kreg[4][4];
    #pragma unroll
    for (int sb = 0; sb < 4; sb++)
      #pragma unroll
      for (int kk = 0; kk < 4; kk++)
        kreg[sb][kk] = *(const u16x8*)(kptr + (size_t)(sb * 16) * 1024 + kk * 32);

    #pragma unroll 1
    for (int t = 0; t < nsteps; t++) {
      const int s0 = t * 64;
      // (1) commit V tile t into Vt[cur] (transposed [d][s])
      #pragma unroll
      for (int e = 0; e < 8; e++) {
        ushort4 w;
        w.x = vreg[0][e]; w.y = vreg[1][e]; w.z = vreg[2][e]; w.w = vreg[3][e];
        *(ushort4*)&Vt[cur][d0s + e][sl4] = w;
      }
      __syncthreads();  // the ONLY barrier per step
      // (2) QK^T from registers: D[s][q], A = K rows, B = Q
      f32x4 sc[4] = {};
      __builtin_amdgcn_s_setprio(1);
      #pragma unroll
      for (int sb = 0; sb < 4; sb++)
        #pragma unroll
        for (int kk = 0; kk < 4; kk++)
          sc[sb] = mfma16(kreg[sb][kk], qf[kk], sc[sb]);
      __builtin_amdgcn_s_setprio(0);
      // (3) prefetch K,V for step t+1 (WAR on kreg/vreg; ~full step to land)
      if (t + 1 < nsteps) {
        #pragma unroll
        for (int sb = 0; sb < 4; sb++)
          #pragma unroll
          for (int kk = 0; kk < 4; kk++)
            kreg[sb][kk] = *(const u16x8*)(kptr + (size_t)((t + 1) * 64 + sb * 16) * 1024 + kk * 32);
        #pragma unroll
        for (int j = 0; j < 4; j++)
          vreg[j] = *(const u16x8*)(vbase + (size_t)((t + 1) * 64 + sl4 + j) * 6144);
      }
      // (4) online softmax, exp2 domain, defer-max
      const int qg = qw + ql;
      float p[4][4];
      float mt = -3e38f;
      #pragma unroll
      for (int sb = 0; sb < 4; sb++)
        #pragma unroll
        for (int r = 0; r < 4; r++) {
          int s = s0 + sb * 16 + kg * 4 + r;
          float v = (s > qg) ? -3e38f : sc[sb][r];
          p[sb][r] = v;
          mt = fmaxf(mt, v);
        }
      mt = fmaxf(mt, __shfl_xor(mt, 16, 64));
      mt = fmaxf(mt, __shfl_xor(mt, 32, 64));
      if (!__all(mt - m_run <= 11.5f)) {
        float m_new = fmaxf(m_run, mt);
        float fco = exp2f(m_run - m_new);
        float fr[4];
        #pragma unroll
        for (int r = 0; r < 4; r++) fr[r] = __shfl(fco, (lane & 48) | (kg * 4 + r), 64);
        #pragma unroll
        for (int db = 0; db < 8; db++)
          #pragma unroll
          for (int r = 0; r < 4; r++) acc[db][r] *= fr[r];
        l_run *= fco;
        m_run = m_new;
      }
      float rs = 0.f;
      #pragma unroll
      for (int sb = 0; sb < 4; sb++)
        #pragma unroll
        for (int r = 0; r < 4; r++) {
          float e = exp2f(p[sb][r] - m_run);
          p[sb][r] = e;
          rs += e;
        }
      rs += __shfl_xor(rs, 16, 64);
      rs += __shfl_xor(rs, 32, 64);
      l_run += rs;
      // (5) P -> per-wave LDS (wave-local)
      #pragma unroll
      for (int sb = 0; sb < 4; sb++) {
        ushort4 pk;
        pk.x = f2bf(p[sb][0]); pk.y = f2bf(p[sb][1]);
        pk.z = f2bf(p[sb][2]); pk.w = f2bf(p[sb][3]);
        *(ushort4*)&Plds[wave][ql][sb * 16 + kg * 4] = pk;
      }
      // (6) PV: A = P[q][s], B = Vt[d][s]
      __builtin_amdgcn_s_setprio(1);
      #pragma unroll
      for (int hf = 0; hf < 2; hf++) {
        u16x8 pf = *(const u16x8*)&Plds[wave][ql][hf * 32 + kg * 8];
        #pragma unroll
        for (int db = 0; db < 8; db++) {
          u16x8 vf = *(const u16x8*)&Vt[cur][db * 16 + ql][hf * 32 + kg * 8];
          acc[db] = mfma16(pf, vf, acc[db]);
        }
      }
      __builtin_amdgcn_s_setprio(0);
      cur ^= 1;
    }

    // epilogue for this q-tile
    float linv[4];
    #pragma unroll
    for (int r = 0; r < 4; r++)
      linv[r] = 1.f / __shfl(l_run, (lane & 48) | (kg * 4 + r), 64);
    #pragma unroll
    for (int db = 0; db < 8; db++) {
      int d = db * 16 + ql;
      #pragma unroll
      for (int r = 0; r < 4; r++) {
        int q = qw + kg * 4 + r;
        out[((size_t)q * 32 + h) * 128 + d] = f2bf(acc[db][r] * linv[r]);
      }
    }
  }
}

// ---------------- launcher ----------------
extern "C" void kernel_launch(void* const* d_in, const int* in_sizes, int n_in,
                              void* d_out, int out_size, void* d_ws, size_t ws_size,
                              hipStream_t stream) {
  const float* x  = (const float*)d_in[0];
  const float* Wq = (const float*)d_in[1];
  const float* Wk = (const float*)d_in[2];
  const float* Wv = (const float*)d_in[3];
  const float* Wo = (const float*)d_in[4];
  const int* start = (const int*)d_in[5];

  const int L = 2048, HID = 4096, NH = 32, NKV = 8;
  const int NQ = 4096, NKVD = 1024, NF = 6144;

  char* ws = (char*)d_ws;
  size_t off = 0;
  auto alloc = [&](size_t bytes) {
    void* p = ws + off;
    off += (bytes + 255) & ~(size_t)255;
    return p;
  };
  u16* x_b   = (u16*)alloc((size_t)L * HID * 2);
  // Wq_t, Wk_t, Wv_t MUST be contiguous (fused GEMM reads them as one
  // 6144-row Bt). Sizes are 256B-multiples so alloc() leaves no gaps.
  u16* Wq_t  = (u16*)alloc((size_t)NQ * HID * 2);
  u16* Wk_t  = (u16*)alloc((size_t)NKVD * HID * 2);
  u16* Wv_t  = (u16*)alloc((size_t)NKVD * HID * 2);
  u16* Wo_t  = (u16*)alloc((size_t)HID * NQ * 2);
  u16* q_r   = (u16*)alloc((size_t)L * NQ * 2);
  u16* k_r   = (u16*)alloc((size_t)L * NKVD * 2);
  float2* tab = (float2*)alloc((size_t)L * 64 * sizeof(float2));
  // fused QKV output lives in d_out (25.2MB < 33.5MB); fully rewritten by the
  // final out-projection afterwards.
  u16* qkv_b  = (u16*)d_out;
  u16* attn_b = Wq_t;  // reuse Wq^T region after the fused GEMM

  const float qscale = 0.08838834764831845f * 1.4426950408889634f;  // 1/sqrt(128)*log2(e)

  // conversions / transposes / table
  cvt_f32_bf16<<<(L * HID / 4 + 255) / 256, 256, 0, stream>>>(x, x_b, L * HID / 4);
  transpose_cvt<<<dim3(HID / 32, NQ / 32), 256, 0, stream>>>(Wq, Wq_t, HID, NQ);
  transpose_cvt<<<dim3(HID / 32, NKVD / 32), 256, 0, stream>>>(Wk, Wk_t, HID, NKVD);
  transpose_cvt<<<dim3(HID / 32, NKVD / 32), 256, 0, stream>>>(Wv, Wv_t, HID, NKVD);
  transpose_cvt<<<dim3(NQ / 32, HID / 32), 256, 0, stream>>>(Wo, Wo_t, NQ, HID);
  rope_table_k<<<(L * 64 + 255) / 256, 256, 0, stream>>>(tab, start, L);

  // fused QKV projection: [2048][6144] bf16 into d_out scratch
  gemm_bt<true><<<dim3(L / 128, NF / 128), 256, 0, stream>>>(x_b, Wq_t, nullptr, qkv_b, L, NF, HID);

  // RoPE: Q (scaled, log2e folded) and K (unscaled), both bf16 in/out
  rope_apply_b<<<(L * NH * 8 + 255) / 256, 256, 0, stream>>>(qkv_b, NF, 0, q_r, tab, L * NH * 8, NH, qscale);
  rope_apply_b<<<(L * NKV * 8 + 255) / 256, 256, 0, stream>>>(qkv_b, NF, NQ, k_r, tab, L * NKV * 8, NKV, 1.0f);

  // attention (V read straight from fused buffer)
  attn_k<<<dim3(16, NH), 256, 0, stream>>>(q_r, k_r, qkv_b, attn_b);

  // output projection (rewrites all of d_out)
  gemm_bt<false><<<dim3(L / 128, HID / 128), 256, 0, stream>>>(attn_b, Wo_t, (float*)d_out, nullptr, L, HID, NQ);
}